// Round 2
// baseline (215.985 us; speedup 1.0000x reference)
//
#include <hip/hip_runtime.h>

// Depthwise 7x7 VALID conv, fp32, NCHW.
// x: (16,256,128,128), w: (256,7,7), out: (16,256,122,122)
// Register sliding-window, no LDS: each thread owns an 8x4 output micro-tile,
// reads 14 rows x 3 float4 from global (L1 serves halo re-reads).

#define BATCH 16
#define CHAN  256
#define H_IN  128
#define W_IN  128
#define KS    7
#define H_OUT 122
#define W_OUT 122

#define RB 8           // output rows per thread
#define CB 4           // output cols per thread

__global__ __launch_bounds__(256)
void dwconv7x7_kernel(const float* __restrict__ x,
                      const float* __restrict__ w,
                      float* __restrict__ out) {
    const int img = blockIdx.y;                 // b*CHAN + c
    const int ch  = img & (CHAN - 1);

    const int tx = threadIdx.x & 31;            // col group: 32 x 4 = 128 cols
    const int ty = threadIdx.x >> 5;            // row group: 8 x 8 = 64 rows

    const int ox = tx * CB;                     // output col base (0..124)
    const int oy = blockIdx.x * 64 + ty * RB;   // output row base

    // ---- weights: uniform address -> scalar loads into SGPRs ----
    const float* __restrict__ wp = w + ch * (KS * KS);
    float wr[KS * KS];
    #pragma unroll
    for (int i = 0; i < KS * KS; ++i) wr[i] = wp[i];

    const float* __restrict__ xp = x + (size_t)img * (H_IN * W_IN);

    // column chunk bases, clamped so float4 loads stay in-bounds
    // (clamped garbage only feeds masked-out outputs)
    const int c0 = ox;
    const int c1 = (ox + 4 <= W_IN - 4) ? ox + 4 : W_IN - 4;
    const int c2 = (ox + 8 <= W_IN - 4) ? ox + 8 : W_IN - 4;

    float acc[RB][CB] = {};

    #pragma unroll
    for (int r = 0; r < RB + KS - 1; ++r) {     // 14 input rows
        int ry = oy + r;
        if (ry > H_IN - 1) ry = H_IN - 1;       // clamp: garbage -> masked rows only
        const float* row = xp + (size_t)ry * W_IN;
        const float4 a0 = *reinterpret_cast<const float4*>(row + c0);
        const float4 a1 = *reinterpret_cast<const float4*>(row + c1);
        const float4 a2 = *reinterpret_cast<const float4*>(row + c2);
        const float win[12] = {a0.x, a0.y, a0.z, a0.w,
                               a1.x, a1.y, a1.z, a1.w,
                               a2.x, a2.y, a2.z, a2.w};
        #pragma unroll
        for (int i = 0; i < RB; ++i) {
            const int ky = r - i;
            if (ky >= 0 && ky < KS) {
                #pragma unroll
                for (int kx = 0; kx < KS; ++kx) {
                    const float wv = wr[ky * KS + kx];
                    #pragma unroll
                    for (int cc = 0; cc < CB; ++cc)
                        acc[i][cc] = fmaf(win[kx + cc], wv, acc[i][cc]);
                }
            }
        }
    }

    // ---- store (float2: rows are 8B-aligned; odd rows break 16B alignment) ----
    float* __restrict__ op = out + (size_t)img * (H_OUT * W_OUT);
    #pragma unroll
    for (int i = 0; i < RB; ++i) {
        const int y = oy + i;
        if (y < H_OUT) {
            float* q = op + (size_t)y * W_OUT + ox;
            if (ox + CB <= W_OUT) {
                *reinterpret_cast<float2*>(q)     = make_float2(acc[i][0], acc[i][1]);
                *reinterpret_cast<float2*>(q + 2) = make_float2(acc[i][2], acc[i][3]);
            } else {
                #pragma unroll
                for (int cc = 0; cc < CB; ++cc)
                    if (ox + cc < W_OUT) q[cc] = acc[i][cc];
            }
        }
    }
}

extern "C" void kernel_launch(void* const* d_in, const int* in_sizes, int n_in,
                              void* d_out, int out_size, void* d_ws, size_t ws_size,
                              hipStream_t stream) {
    const float* x = (const float*)d_in[0];
    const float* w = (const float*)d_in[1];
    float* out = (float*)d_out;

    // block covers 128 cols x 64 rows of output; 2 row-blocks x 4096 images
    dim3 grid(2, BATCH * CHAN, 1);
    dim3 block(256, 1, 1);
    dwconv7x7_kernel<<<grid, block, 0, stream>>>(x, w, out);
}